// Round 7
// baseline (197.325 us; speedup 1.0000x reference)
//
#include <hip/hip_runtime.h>

typedef unsigned short u16;
typedef unsigned int u32;
typedef __attribute__((ext_vector_type(8))) __bf16 bf16x8;
typedef __attribute__((ext_vector_type(4))) float f32x4;

__device__ __forceinline__ u16 f2bf(float f) {
  unsigned u = __float_as_uint(f);
  u += 0x7FFFu + ((u >> 16) & 1u);   // round-to-nearest-even
  return (u16)(u >> 16);
}

__device__ __forceinline__ float fast_exp2(float x) { return __builtin_amdgcn_exp2f(x); }
__device__ __forceinline__ float fast_rcp(float x) { return __builtin_amdgcn_rcpf(x); }

// ---------------- merged f32 -> bf16 conversions (one dispatch) ----------------
// seg0: x (mask-folded, 2097152 f4)  seg1: Wq (*0.125*log2e, 262144 f4)
// seg2: y (786432 f4)                seg3: Wkv (393216 f4)   total 3538944 f4
__global__ void cvt_all(const float* __restrict__ x, const float* __restrict__ Wq,
                        const float* __restrict__ y, const float* __restrict__ Wkv,
                        const int* __restrict__ mask,
                        u16* __restrict__ Xb, u16* __restrict__ Wqb,
                        u16* __restrict__ Yb, u16* __restrict__ Wkvb) {
  int i = blockIdx.x * 256 + threadIdx.x;
  const float4* src;
  u16* dst;
  int j;
  float sc;
  if (i < 2097152) {
    j = i; src = (const float4*)x; dst = Xb;
    sc = (mask[i >> 8] != 0) ? 1.0f : 0.0f;  // masked q-rows -> Q=0 -> uniform softmax
  } else if (i < 2359296) {
    j = i - 2097152; src = (const float4*)Wq; dst = Wqb;
    sc = 0.18033688f;  // d^-0.5 * log2(e): softmax exp via single v_exp_f32 (base-2)
  } else if (i < 3145728) {
    j = i - 2359296; src = (const float4*)y; dst = Yb;
    sc = 1.0f;
  } else {
    j = i - 3145728; src = (const float4*)Wkv; dst = Wkvb;
    sc = 1.0f;
  }
  float4 v = src[j];
  ushort4 o;
  o.x = f2bf(v.x * sc);
  o.y = f2bf(v.y * sc);
  o.z = f2bf(v.z * sc);
  o.w = f2bf(v.w * sc);
  ((ushort4*)dst)[j] = o;
}

// ---------------- merged dual bf16 GEMM: C[M,N] = A[M,K] * B[N,K]^T ----------------
// m97 tile geometry (128x128, BK=32, 4 waves, 16x16x32 MFMA, gload_lds w=16).
// R7: (a) tile remap for XCD A-panel locality: same-bx blocks are == mod 8 ->
// same XCD L2 -> each A-panel fetched from HBM once per XCD (was up to 8x;
// FETCH 94MB -> ~60MB). (b) depth-2 prefetch: 3 LDS buffers + counted
// s_waitcnt vmcnt(4) + raw s_barrier (T4/m218 pattern) so the newest stage's
// 4 loads stay in flight across the barrier -> ~600cy latency coverage vs
// ~300 with the full-drain __syncthreads (A loads are HBM misses ~900cy).
__global__ __launch_bounds__(256) void gemm_dual(
    const u16* __restrict__ Aq, const u16* __restrict__ Bq, u16* __restrict__ Cq,
    const u16* __restrict__ Akv, const u16* __restrict__ Bkv, u16* __restrict__ Ckv) {
  __shared__ __align__(16) u16 sA[3 * 128 * 32];
  __shared__ __align__(16) u16 sB[3 * 128 * 32];
  const int t = threadIdx.x;
  const int wave = t >> 6;
  const int lane = t & 63;
  const int wm = (wave >> 1) * 64;
  const int wn = (wave & 1) * 64;
  const int fr = lane & 15;
  const int quad = lane >> 4;
  const int fk = quad * 8;
  const int sr = lane >> 2;
  const int sc = (lane & 3) * 8;

  const u16 *A, *B;
  u16* C;
  int N, K, bx, by;
  const int blk = blockIdx.x;
  if (blk < 512) {
    A = Aq; B = Bq; C = Cq; N = 1024; K = 1024;
    by = blk >> 6; bx = blk & 63;           // 64 x 8 tiles, M=8192; same bx -> same XCD
  } else {
    A = Akv; B = Bkv; C = Ckv; N = 2048; K = 768;
    const int id = blk - 512;
    by = id >> 5; bx = id & 31;             // 32 x 16 tiles, M=4096; same bx -> same XCD
  }
  const int STEPS = K >> 5;

  f32x4 acc[4][4];
  const f32x4 z4 = {0.f, 0.f, 0.f, 0.f};
#pragma unroll
  for (int i = 0; i < 4; ++i)
#pragma unroll
    for (int j = 0; j < 4; ++j) acc[i][j] = z4;

  const u16* Abase = A + (size_t)bx * 128 * K;
  const u16* Bbase = B + (size_t)by * 128 * K;

  auto stage = [&](int k0, u16* dA, u16* dB) {
#pragma unroll
    for (int q = 0; q < 2; ++q) {
      const int chunk = wave * 2 + q;
      const int row = chunk * 16 + sr;
      __builtin_amdgcn_global_load_lds(
          (__attribute__((address_space(1))) void*)(Abase + (size_t)row * K + k0 + sc),
          (__attribute__((address_space(3))) void*)(dA + chunk * 512), 16, 0, 0);
      __builtin_amdgcn_global_load_lds(
          (__attribute__((address_space(1))) void*)(Bbase + (size_t)row * K + k0 + sc),
          (__attribute__((address_space(3))) void*)(dB + chunk * 512), 16, 0, 0);
    }
  };

  // prologue: fill buffers 0 and 1 (4 loads each); wait only for buffer 0.
  stage(0, sA, sB);
  stage(32, sA + 4096, sB + 4096);
  asm volatile("s_waitcnt vmcnt(4)" ::: "memory");
  __builtin_amdgcn_s_barrier();

  for (int it = 0; it < STEPS; ++it) {
    const int cur = it % 3;
    u16* cA = sA + cur * 4096;
    u16* cB = sB + cur * 4096;
    // depth-2 prefetch into buffer (it+2)%3 (fully read in iter it-1, barrier-protected)
    if (it + 2 < STEPS)
      stage((it + 2) * 32, sA + ((it + 2) % 3) * 4096, sB + ((it + 2) % 3) * 4096);

    bf16x8 af[4], bfv[4];
#pragma unroll
    for (int i = 0; i < 4; ++i)
      af[i] = *(const bf16x8*)(cA + (wm + i * 16 + fr) * 32 + fk);
#pragma unroll
    for (int j = 0; j < 4; ++j)
      bfv[j] = *(const bf16x8*)(cB + (wn + j * 16 + fr) * 32 + fk);
#pragma unroll
    for (int i = 0; i < 4; ++i)
#pragma unroll
      for (int j = 0; j < 4; ++j)
        acc[i][j] = __builtin_amdgcn_mfma_f32_16x16x32_bf16(af[i], bfv[j], acc[i][j], 0, 0, 0);

    // counted drain: oldest stage (buf it+1) must land; newest stays in flight.
    if (it + 1 < STEPS) {
      if (it + 2 < STEPS) asm volatile("s_waitcnt vmcnt(4)" ::: "memory");
      else                asm volatile("s_waitcnt vmcnt(0)" ::: "memory");
      __builtin_amdgcn_s_barrier();
    }
  }

#pragma unroll
  for (int i = 0; i < 4; ++i)
#pragma unroll
    for (int j = 0; j < 4; ++j)
#pragma unroll
      for (int r = 0; r < 4; ++r) {
        const int row = bx * 128 + wm + i * 16 + quad * 4 + r;
        const int col = by * 128 + wn + j * 16 + fr;
        C[(size_t)row * N + col] = f2bf(acc[i][j][r]);
      }
}

// ---------------- transpose V half of KV into Vt[b,h,d, sigma(N2)] ----------------
// sigma for in-register P (swapped QK^T): PV A-frag slot pos (within 32-group,
// pos = quad*8 + j) must hold key sigma(pos) = ((j>>2)<<4) | (quad<<2) | (j&3).
// Inverse (key n2 -> pos): pos = (((n2>>2)&3)<<3) | (((n2>>4)&1)<<2) | (n2&3).
__global__ void transpose_v(const u16* __restrict__ KV, u16* __restrict__ Vt) {
  __shared__ u16 tile[64][66];
  const int t = threadIdx.x;
  const int rb = blockIdx.x * 64;
  const int h = blockIdx.y;
#pragma unroll
  for (int i = 0; i < 16; ++i) {
    int idx = i * 256 + t;
    int r = idx >> 6, c = idx & 63;
    tile[r][c] = KV[(size_t)(rb + r) * 2048 + 1024 + h * 64 + c];
  }
  __syncthreads();
  const int b = blockIdx.x >> 4;
  const int n2b = (blockIdx.x & 15) * 64;
#pragma unroll
  for (int i = 0; i < 16; ++i) {
    int idx = i * 256 + t;
    int dd = idx >> 6, n2 = idx & 63;
    int cperm = (n2 & 32) | (((n2 >> 2) & 3) << 3) | (((n2 >> 4) & 1) << 2) | (n2 & 3);
    Vt[(size_t)((b * 16 + h) * 64 + dd) * 1024 + n2b + cperm] = tile[n2][dd];
  }
}

// ---------------- fused flash attention (in-register P + gload_lds double-buffer) ----------------
// R5 (passed, 45.5us): swapped QK^T in-register P, fixed-max softmax, double-buffered
// LDS via global_load_lds, one barrier per kc, both-sides XOR chunk-swizzle.
// UNCHANGED this round (isolate the GEMM variable).
__global__ __launch_bounds__(256, 2) void attn_kernel(
    const u16* __restrict__ Q, const u16* __restrict__ KV,
    const u16* __restrict__ Vt, float* __restrict__ Out) {
  __shared__ __align__(16) u16 sK[2 * 128 * 64];   // [buf][key][dd], swizzled chunks
  __shared__ __align__(16) u16 sV[2 * 64 * 128];   // [buf][dd][perm key], swizzled chunks
  __shared__ float red[4][2][4][16];               // [wave][hh][quad][fr] partial denoms

  const int t = threadIdx.x;
  const int wave = t >> 6;
  const int lane = t & 63;
  // XCD swizzle: all 16 q-tiles of one (b,h) are == mod 64 -> same XCD L2.
  const int g = blockIdx.x & 63;
  const int qt = blockIdx.x >> 6;   // 0..15
  const int b = g >> 4;
  const int h = g & 15;
  const int q0 = qt * 128;
  const int fr = lane & 15;
  const int quad = lane >> 4;
  const int l3 = lane >> 3, l7 = lane & 7;     // K staging decomposition
  const int l4 = lane >> 4, l15 = lane & 15;   // V staging decomposition

  // Q fragments for both halves (kc-invariant, from global once).
  const u16* qbase = Q + (size_t)(b * 2048 + q0 + wave * 16 + fr) * 1024 + h * 64 + quad * 8;
  bf16x8 qa[2][2];
  qa[0][0] = *(const bf16x8*)(qbase);
  qa[0][1] = *(const bf16x8*)(qbase + 32);
  qa[1][0] = *(const bf16x8*)(qbase + (size_t)64 * 1024);
  qa[1][1] = *(const bf16x8*)(qbase + (size_t)64 * 1024 + 32);

  // ---- staging: 16 K-loads (8 rows x 128B each) + 16 V-loads (4 rows x 256B each)
  // K: load j covers rows 8j..8j+7; lane l -> row 8j+l3, stores LDS chunk l7,
  //    sources global col16 = l7 ^ l3 (so LDS chunk c holds col c^(row&7)).
  // V: load j covers rows 4j..4j+3; lane l -> row 4j+l4, stores LDS chunk l15,
  //    sources global chunk = l15 ^ (4*(j&1)+l4).
  const int kq = (l7 ^ l3) * 8;                  // K src col offset (u16)
  auto stage = [&](int kcn, u16* dK, u16* dV) {
#pragma unroll
    for (int i = 0; i < 4; ++i) {
      const int j = wave * 4 + i;
      const u16* ksrc = KV + (size_t)(b * 1024 + kcn * 128 + 8 * j + l3) * 2048 + h * 64 + kq;
      __builtin_amdgcn_global_load_lds(
          (__attribute__((address_space(1))) void*)ksrc,
          (__attribute__((address_space(3))) void*)(dK + j * 512), 16, 0, 0);
      const int vq = (l15 ^ ((i & 1) * 4 + l4)) * 8;   // V src chunk offset (u16)
      const u16* vsrc = Vt + (size_t)((b * 16 + h) * 64 + 4 * j + l4) * 1024 + kcn * 128 + vq;
      __builtin_amdgcn_global_load_lds(
          (__attribute__((address_space(1))) void*)vsrc,
          (__attribute__((address_space(3))) void*)(dV + j * 512), 16, 0, 0);
    }
  };

  stage(0, sK, sV);
  __syncthreads();   // compiler drains vmcnt before the barrier

  const f32x4 z4 = {0.f, 0.f, 0.f, 0.f};
  f32x4 o[2][4];
  float l_run[2] = {0.f, 0.f};
#pragma unroll
  for (int hh = 0; hh < 2; ++hh)
#pragma unroll
    for (int nt = 0; nt < 4; ++nt) o[hh][nt] = z4;

  // swizzled read chunk offsets (u16): chunk q of row r lives at (q^(r&7))*8; r&7==fr&7
  const int f7 = fr & 7;
  const int ck0 = (quad ^ f7) * 8;          // K chunk quad
  const int ck1 = ((quad ^ 4) ^ f7) * 8;    // K chunk quad+4

  for (int kc = 0; kc < 8; ++kc) {
    const u16* sKc = sK + (kc & 1) * 8192;
    const u16* sVc = sV + (kc & 1) * 8192;
    // issue next chunk's prefetch into the other buffer (completes under compute)
    if (kc < 7) stage(kc + 1, sK + ((kc + 1) & 1) * 8192, sV + ((kc + 1) & 1) * 8192);

    // Streamed per 32-key slice: QK^T -> exp2 -> pack -> PV (fixed-max, no S matrix).
#pragma unroll
    for (int ks = 0; ks < 4; ++ks) {
      f32x4 s0[2], s1[2];   // [hh], nt=2ks and 2ks+1
      {
        const u16* kb = sKc + ((2 * ks) * 16 + fr) * 64;
        bf16x8 k0 = *(const bf16x8*)(kb + ck0);
        bf16x8 k1 = *(const bf16x8*)(kb + ck1);
        s0[0] = __builtin_amdgcn_mfma_f32_16x16x32_bf16(k0, qa[0][0], z4, 0, 0, 0);
        s0[0] = __builtin_amdgcn_mfma_f32_16x16x32_bf16(k1, qa[0][1], s0[0], 0, 0, 0);
        s0[1] = __builtin_amdgcn_mfma_f32_16x16x32_bf16(k0, qa[1][0], z4, 0, 0, 0);
        s0[1] = __builtin_amdgcn_mfma_f32_16x16x32_bf16(k1, qa[1][1], s0[1], 0, 0, 0);
      }
      {
        const u16* kb = sKc + ((2 * ks + 1) * 16 + fr) * 64;
        bf16x8 k0 = *(const bf16x8*)(kb + ck0);
        bf16x8 k1 = *(const bf16x8*)(kb + ck1);
        s1[0] = __builtin_amdgcn_mfma_f32_16x16x32_bf16(k0, qa[0][0], z4, 0, 0, 0);
        s1[0] = __builtin_amdgcn_mfma_f32_16x16x32_bf16(k1, qa[0][1], s1[0], 0, 0, 0);
        s1[1] = __builtin_amdgcn_mfma_f32_16x16x32_bf16(k0, qa[1][0], z4, 0, 0, 0);
        s1[1] = __builtin_amdgcn_mfma_f32_16x16x32_bf16(k1, qa[1][1], s1[1], 0, 0, 0);
      }

      // P = 2^s in-register; pack into PV A-fragment (key order matches Vt's sigma):
      // elem j=0..3 <- s0[r] (keys quad*4+r), j=4..7 <- s1[r] (keys 16+quad*4+r).
      bf16x8 pa[2];
#pragma unroll
      for (int hh = 0; hh < 2; ++hh) {
        f32x4& a = (hh == 0) ? s0[0] : s0[1];
        f32x4& bb = (hh == 0) ? s1[0] : s1[1];
        float l = 0.f;
#pragma unroll
        for (int r = 0; r < 4; ++r) {
          float p0 = fast_exp2(a[r]); a[r] = p0; l += p0;
          float p1 = fast_exp2(bb[r]); bb[r] = p1; l += p1;
        }
        l_run[hh] += l;
        bf16x8 pv;
        pv[0] = (__bf16)a[0];  pv[1] = (__bf16)a[1];
        pv[2] = (__bf16)a[2];  pv[3] = (__bf16)a[3];
        pv[4] = (__bf16)bb[0]; pv[5] = (__bf16)bb[1];
        pv[6] = (__bf16)bb[2]; pv[7] = (__bf16)bb[3];
        pa[hh] = pv;
      }

      // PV: O[q][dd] += P * V ; vb shared across both halves
#pragma unroll
      for (int ntd = 0; ntd < 4; ++ntd) {
        const int cv = (((ks * 4 + quad) ^ f7)) * 8;   // V chunk ks*4+quad, swizzled
        bf16x8 vb = *(const bf16x8*)(sVc + (ntd * 16 + fr) * 128 + cv);
        o[0][ntd] = __builtin_amdgcn_mfma_f32_16x16x32_bf16(pa[0], vb, o[0][ntd], 0, 0, 0);
        o[1][ntd] = __builtin_amdgcn_mfma_f32_16x16x32_bf16(pa[1], vb, o[1][ntd], 0, 0, 0);
      }
    }

    if (kc < 7) __syncthreads();   // prefetch drained (vmcnt0) + all reads of cur done
  }

  // Denominator reduction via per-wave LDS scratch: lane(fr,quad) holds the
  // partial sum for q=fr over keys == quad*4+{0..3} (mod 16). Sum the 4 quads.
  red[wave][0][quad][fr] = l_run[0];
  red[wave][1][quad][fr] = l_run[1];
  __syncthreads();

#pragma unroll
  for (int hh = 0; hh < 2; ++hh) {
    float inv[4];
#pragma unroll
    for (int r = 0; r < 4; ++r) {
      const int ql = quad * 4 + r;   // q-within-16 of output row
      float d = red[wave][hh][0][ql] + red[wave][hh][1][ql] +
                red[wave][hh][2][ql] + red[wave][hh][3][ql];
      inv[r] = fast_rcp(d);
    }
#pragma unroll
    for (int ntd = 0; ntd < 4; ++ntd)
#pragma unroll
      for (int r = 0; r < 4; ++r) {
        const int row = q0 + hh * 64 + wave * 16 + quad * 4 + r;
        const int col = h * 64 + ntd * 16 + fr;
        Out[(size_t)(b * 2048 + row) * 1024 + col] = o[hh][ntd][r] * inv[r];
      }
  }
}

// ---------------- launch ----------------
extern "C" void kernel_launch(void* const* d_in, const int* in_sizes, int n_in,
                              void* d_out, int out_size, void* d_ws, size_t ws_size,
                              hipStream_t stream) {
  (void)in_sizes; (void)n_in; (void)out_size; (void)ws_size;
  const float* x   = (const float*)d_in[0];   // [4,2048,1024]
  const float* y   = (const float*)d_in[1];   // [4,1024,768]
  const int*   msk = (const int*)d_in[2];     // [4,2048]
  const float* Wq  = (const float*)d_in[3];   // [1024,1024]
  const float* Wkv = (const float*)d_in[4];   // [2048,768]
  float* out = (float*)d_out;                 // [4,2048,1024] f32

  char* ws = (char*)d_ws;
  const size_t MB = 1024 * 1024;
  u16* Xb   = (u16*)(ws + 0);        // 16 MB [8192][1024] mask-folded (dead after gemms)
  u16* Wqb  = (u16*)(ws + 16 * MB);  //  2 MB [1024][1024] * d^-0.5 * log2e
  u16* Yb   = (u16*)(ws + 18 * MB);  //  6 MB [4096][768]
  u16* Wkvb = (u16*)(ws + 24 * MB);  //  3 MB [2048][768]
  u16* Qb   = (u16*)(ws + 27 * MB);  // 16 MB [8192][1024]
  u16* KVb  = (u16*)(ws + 43 * MB);  // 16 MB [4096][2048]
  u16* Vtb  = (u16*)(ws + 59 * MB);  //  8 MB [4096][1024]  (high-water 67 MB)

  cvt_all<<<13824, 256, 0, stream>>>(x, Wq, y, Wkv, msk, Xb, Wqb, Yb, Wkvb);
  gemm_dual<<<1024, 256, 0, stream>>>(Xb, Wqb, Qb, Yb, Wkvb, KVb);
  transpose_v<<<dim3(64, 16), 256, 0, stream>>>(KVb, Vtb);
  attn_kernel<<<1024, 256, 0, stream>>>(Qb, KVb, Vtb, out);
}

// Round 8
// 189.811 us; speedup vs baseline: 1.0396x; 1.0396x over previous
//
#include <hip/hip_runtime.h>

typedef unsigned short u16;
typedef unsigned int u32;
typedef __attribute__((ext_vector_type(8))) __bf16 bf16x8;
typedef __attribute__((ext_vector_type(4))) float f32x4;

__device__ __forceinline__ u16 f2bf(float f) {
  unsigned u = __float_as_uint(f);
  u += 0x7FFFu + ((u >> 16) & 1u);   // round-to-nearest-even
  return (u16)(u >> 16);
}

__device__ __forceinline__ float fast_exp2(float x) { return __builtin_amdgcn_exp2f(x); }
__device__ __forceinline__ float fast_rcp(float x) { return __builtin_amdgcn_rcpf(x); }

// ---------------- merged f32 -> bf16 conversions (one dispatch) ----------------
// seg0: x (mask-folded, 2097152 f4)  seg1: Wq (*0.125*log2e, 262144 f4)
// seg2: y (786432 f4)                seg3: Wkv (393216 f4)   total 3538944 f4
__global__ void cvt_all(const float* __restrict__ x, const float* __restrict__ Wq,
                        const float* __restrict__ y, const float* __restrict__ Wkv,
                        const int* __restrict__ mask,
                        u16* __restrict__ Xb, u16* __restrict__ Wqb,
                        u16* __restrict__ Yb, u16* __restrict__ Wkvb) {
  int i = blockIdx.x * 256 + threadIdx.x;
  const float4* src;
  u16* dst;
  int j;
  float sc;
  if (i < 2097152) {
    j = i; src = (const float4*)x; dst = Xb;
    sc = (mask[i >> 8] != 0) ? 1.0f : 0.0f;  // masked q-rows -> Q=0 -> uniform softmax
  } else if (i < 2359296) {
    j = i - 2097152; src = (const float4*)Wq; dst = Wqb;
    sc = 0.18033688f;  // d^-0.5 * log2(e): softmax exp via single v_exp_f32 (base-2)
  } else if (i < 3145728) {
    j = i - 2359296; src = (const float4*)y; dst = Yb;
    sc = 1.0f;
  } else {
    j = i - 3145728; src = (const float4*)Wkv; dst = Wkvb;
    sc = 1.0f;
  }
  float4 v = src[j];
  ushort4 o;
  o.x = f2bf(v.x * sc);
  o.y = f2bf(v.y * sc);
  o.z = f2bf(v.z * sc);
  o.w = f2bf(v.w * sc);
  ((ushort4*)dst)[j] = o;
}

// ---------------- merged dual bf16 GEMM: C[M,N] = A[M,K] * B[N,K]^T ----------------
// m97 tile geometry (128x128, BK=32, 4 waves, 16x16x32 MFMA, gload_lds w=16).
// R8 = R6-proven transport (2-buffer LDS, depth-1 prefetch issued before compute,
// ONE plain __syncthreads per K-step; compiler owns waitcnts -- R7's hand-rolled
// counted-vmcnt/%3 pipeline tripled VALU work and regressed) + R7-proven XCD
// tile remap (same-bx blocks == mod 8 -> same XCD L2 -> A-panel fetched from HBM
// once per XCD; FETCH 94MB -> 35MB measured). With A loads L2-resident (~250cy),
// depth-1 prefetch + full drain covers the latency.
__global__ __launch_bounds__(256) void gemm_dual(
    const u16* __restrict__ Aq, const u16* __restrict__ Bq, u16* __restrict__ Cq,
    const u16* __restrict__ Akv, const u16* __restrict__ Bkv, u16* __restrict__ Ckv) {
  __shared__ __align__(16) u16 sA[2 * 128 * 32];
  __shared__ __align__(16) u16 sB[2 * 128 * 32];
  const int t = threadIdx.x;
  const int wave = t >> 6;
  const int lane = t & 63;
  const int wm = (wave >> 1) * 64;
  const int wn = (wave & 1) * 64;
  const int fr = lane & 15;
  const int quad = lane >> 4;
  const int fk = quad * 8;
  const int sr = lane >> 2;
  const int sc = (lane & 3) * 8;

  const u16 *A, *B;
  u16* C;
  int N, K, bx, by;
  const int blk = blockIdx.x;
  if (blk < 512) {
    A = Aq; B = Bq; C = Cq; N = 1024; K = 1024;
    by = blk >> 6; bx = blk & 63;           // 64 x 8 tiles, M=8192; same bx -> same XCD
  } else {
    A = Akv; B = Bkv; C = Ckv; N = 2048; K = 768;
    const int id = blk - 512;
    by = id >> 5; bx = id & 31;             // 32 x 16 tiles, M=4096; same bx -> same XCD
  }

  f32x4 acc[4][4];
  const f32x4 z4 = {0.f, 0.f, 0.f, 0.f};
#pragma unroll
  for (int i = 0; i < 4; ++i)
#pragma unroll
    for (int j = 0; j < 4; ++j) acc[i][j] = z4;

  const u16* Abase = A + (size_t)bx * 128 * K;
  const u16* Bbase = B + (size_t)by * 128 * K;

  auto stage = [&](int k0, u16* dA, u16* dB) {
#pragma unroll
    for (int q = 0; q < 2; ++q) {
      const int chunk = wave * 2 + q;
      const int row = chunk * 16 + sr;
      __builtin_amdgcn_global_load_lds(
          (__attribute__((address_space(1))) void*)(Abase + (size_t)row * K + k0 + sc),
          (__attribute__((address_space(3))) void*)(dA + chunk * 512), 16, 0, 0);
      __builtin_amdgcn_global_load_lds(
          (__attribute__((address_space(1))) void*)(Bbase + (size_t)row * K + k0 + sc),
          (__attribute__((address_space(3))) void*)(dB + chunk * 512), 16, 0, 0);
    }
  };

  stage(0, sA, sB);
  __syncthreads();   // vmcnt drained before barrier -> buf0 ready

  int it = 0;
  for (int k0 = 0; k0 < K; k0 += 32, ++it) {
    u16* cA = sA + (it & 1) * 4096;
    u16* cB = sB + (it & 1) * 4096;
    // prefetch next K-step into the other buffer; completes under compute
    if (k0 + 32 < K) stage(k0 + 32, sA + ((it + 1) & 1) * 4096, sB + ((it + 1) & 1) * 4096);

    bf16x8 af[4], bfv[4];
#pragma unroll
    for (int i = 0; i < 4; ++i)
      af[i] = *(const bf16x8*)(cA + (wm + i * 16 + fr) * 32 + fk);
#pragma unroll
    for (int j = 0; j < 4; ++j)
      bfv[j] = *(const bf16x8*)(cB + (wn + j * 16 + fr) * 32 + fk);
#pragma unroll
    for (int i = 0; i < 4; ++i)
#pragma unroll
      for (int j = 0; j < 4; ++j)
        acc[i][j] = __builtin_amdgcn_mfma_f32_16x16x32_bf16(af[i], bfv[j], acc[i][j], 0, 0, 0);

    // one barrier per K-step: prefetch drained (vmcnt0) + all reads of cur done
    if (k0 + 32 < K) __syncthreads();
  }

#pragma unroll
  for (int i = 0; i < 4; ++i)
#pragma unroll
    for (int j = 0; j < 4; ++j)
#pragma unroll
      for (int r = 0; r < 4; ++r) {
        const int row = bx * 128 + wm + i * 16 + quad * 4 + r;
        const int col = by * 128 + wn + j * 16 + fr;
        C[(size_t)row * N + col] = f2bf(acc[i][j][r]);
      }
}

// ---------------- transpose V half of KV into Vt[b,h,d, sigma(N2)] ----------------
// sigma for in-register P (swapped QK^T): PV A-frag slot pos (within 32-group,
// pos = quad*8 + j) must hold key sigma(pos) = ((j>>2)<<4) | (quad<<2) | (j&3).
// Inverse (key n2 -> pos): pos = (((n2>>2)&3)<<3) | (((n2>>4)&1)<<2) | (n2&3).
__global__ void transpose_v(const u16* __restrict__ KV, u16* __restrict__ Vt) {
  __shared__ u16 tile[64][66];
  const int t = threadIdx.x;
  const int rb = blockIdx.x * 64;
  const int h = blockIdx.y;
#pragma unroll
  for (int i = 0; i < 16; ++i) {
    int idx = i * 256 + t;
    int r = idx >> 6, c = idx & 63;
    tile[r][c] = KV[(size_t)(rb + r) * 2048 + 1024 + h * 64 + c];
  }
  __syncthreads();
  const int b = blockIdx.x >> 4;
  const int n2b = (blockIdx.x & 15) * 64;
#pragma unroll
  for (int i = 0; i < 16; ++i) {
    int idx = i * 256 + t;
    int dd = idx >> 6, n2 = idx & 63;
    int cperm = (n2 & 32) | (((n2 >> 2) & 3) << 3) | (((n2 >> 4) & 1) << 2) | (n2 & 3);
    Vt[(size_t)((b * 16 + h) * 64 + dd) * 1024 + n2b + cperm] = tile[n2][dd];
  }
}

// ---------------- fused flash attention (in-register P + gload_lds double-buffer) ----------------
// R5 (passed, 45.5us): swapped QK^T in-register P, fixed-max softmax, double-buffered
// LDS via global_load_lds, one barrier per kc, both-sides XOR chunk-swizzle.
// UNCHANGED this round (isolate the GEMM variable).
__global__ __launch_bounds__(256, 2) void attn_kernel(
    const u16* __restrict__ Q, const u16* __restrict__ KV,
    const u16* __restrict__ Vt, float* __restrict__ Out) {
  __shared__ __align__(16) u16 sK[2 * 128 * 64];   // [buf][key][dd], swizzled chunks
  __shared__ __align__(16) u16 sV[2 * 64 * 128];   // [buf][dd][perm key], swizzled chunks
  __shared__ float red[4][2][4][16];               // [wave][hh][quad][fr] partial denoms

  const int t = threadIdx.x;
  const int wave = t >> 6;
  const int lane = t & 63;
  // XCD swizzle: all 16 q-tiles of one (b,h) are == mod 64 -> same XCD L2.
  const int g = blockIdx.x & 63;
  const int qt = blockIdx.x >> 6;   // 0..15
  const int b = g >> 4;
  const int h = g & 15;
  const int q0 = qt * 128;
  const int fr = lane & 15;
  const int quad = lane >> 4;
  const int l3 = lane >> 3, l7 = lane & 7;     // K staging decomposition
  const int l4 = lane >> 4, l15 = lane & 15;   // V staging decomposition

  // Q fragments for both halves (kc-invariant, from global once).
  const u16* qbase = Q + (size_t)(b * 2048 + q0 + wave * 16 + fr) * 1024 + h * 64 + quad * 8;
  bf16x8 qa[2][2];
  qa[0][0] = *(const bf16x8*)(qbase);
  qa[0][1] = *(const bf16x8*)(qbase + 32);
  qa[1][0] = *(const bf16x8*)(qbase + (size_t)64 * 1024);
  qa[1][1] = *(const bf16x8*)(qbase + (size_t)64 * 1024 + 32);

  // ---- staging: 16 K-loads (8 rows x 128B each) + 16 V-loads (4 rows x 256B each)
  // K: load j covers rows 8j..8j+7; lane l -> row 8j+l3, stores LDS chunk l7,
  //    sources global col16 = l7 ^ l3 (so LDS chunk c holds col c^(row&7)).
  // V: load j covers rows 4j..4j+3; lane l -> row 4j+l4, stores LDS chunk l15,
  //    sources global chunk = l15 ^ (4*(j&1)+l4).
  const int kq = (l7 ^ l3) * 8;                  // K src col offset (u16)
  auto stage = [&](int kcn, u16* dK, u16* dV) {
#pragma unroll
    for (int i = 0; i < 4; ++i) {
      const int j = wave * 4 + i;
      const u16* ksrc = KV + (size_t)(b * 1024 + kcn * 128 + 8 * j + l3) * 2048 + h * 64 + kq;
      __builtin_amdgcn_global_load_lds(
          (__attribute__((address_space(1))) void*)ksrc,
          (__attribute__((address_space(3))) void*)(dK + j * 512), 16, 0, 0);
      const int vq = (l15 ^ ((i & 1) * 4 + l4)) * 8;   // V src chunk offset (u16)
      const u16* vsrc = Vt + (size_t)((b * 16 + h) * 64 + 4 * j + l4) * 1024 + kcn * 128 + vq;
      __builtin_amdgcn_global_load_lds(
          (__attribute__((address_space(1))) void*)vsrc,
          (__attribute__((address_space(3))) void*)(dV + j * 512), 16, 0, 0);
    }
  };

  stage(0, sK, sV);
  __syncthreads();   // compiler drains vmcnt before the barrier

  const f32x4 z4 = {0.f, 0.f, 0.f, 0.f};
  f32x4 o[2][4];
  float l_run[2] = {0.f, 0.f};
#pragma unroll
  for (int hh = 0; hh < 2; ++hh)
#pragma unroll
    for (int nt = 0; nt < 4; ++nt) o[hh][nt] = z4;

  // swizzled read chunk offsets (u16): chunk q of row r lives at (q^(r&7))*8; r&7==fr&7
  const int f7 = fr & 7;
  const int ck0 = (quad ^ f7) * 8;          // K chunk quad
  const int ck1 = ((quad ^ 4) ^ f7) * 8;    // K chunk quad+4

  for (int kc = 0; kc < 8; ++kc) {
    const u16* sKc = sK + (kc & 1) * 8192;
    const u16* sVc = sV + (kc & 1) * 8192;
    // issue next chunk's prefetch into the other buffer (completes under compute)
    if (kc < 7) stage(kc + 1, sK + ((kc + 1) & 1) * 8192, sV + ((kc + 1) & 1) * 8192);

    // Streamed per 32-key slice: QK^T -> exp2 -> pack -> PV (fixed-max, no S matrix).
#pragma unroll
    for (int ks = 0; ks < 4; ++ks) {
      f32x4 s0[2], s1[2];   // [hh], nt=2ks and 2ks+1
      {
        const u16* kb = sKc + ((2 * ks) * 16 + fr) * 64;
        bf16x8 k0 = *(const bf16x8*)(kb + ck0);
        bf16x8 k1 = *(const bf16x8*)(kb + ck1);
        s0[0] = __builtin_amdgcn_mfma_f32_16x16x32_bf16(k0, qa[0][0], z4, 0, 0, 0);
        s0[0] = __builtin_amdgcn_mfma_f32_16x16x32_bf16(k1, qa[0][1], s0[0], 0, 0, 0);
        s0[1] = __builtin_amdgcn_mfma_f32_16x16x32_bf16(k0, qa[1][0], z4, 0, 0, 0);
        s0[1] = __builtin_amdgcn_mfma_f32_16x16x32_bf16(k1, qa[1][1], s0[1], 0, 0, 0);
      }
      {
        const u16* kb = sKc + ((2 * ks + 1) * 16 + fr) * 64;
        bf16x8 k0 = *(const bf16x8*)(kb + ck0);
        bf16x8 k1 = *(const bf16x8*)(kb + ck1);
        s1[0] = __builtin_amdgcn_mfma_f32_16x16x32_bf16(k0, qa[0][0], z4, 0, 0, 0);
        s1[0] = __builtin_amdgcn_mfma_f32_16x16x32_bf16(k1, qa[0][1], s1[0], 0, 0, 0);
        s1[1] = __builtin_amdgcn_mfma_f32_16x16x32_bf16(k0, qa[1][0], z4, 0, 0, 0);
        s1[1] = __builtin_amdgcn_mfma_f32_16x16x32_bf16(k1, qa[1][1], s1[1], 0, 0, 0);
      }

      // P = 2^s in-register; pack into PV A-fragment (key order matches Vt's sigma):
      // elem j=0..3 <- s0[r] (keys quad*4+r), j=4..7 <- s1[r] (keys 16+quad*4+r).
      bf16x8 pa[2];
#pragma unroll
      for (int hh = 0; hh < 2; ++hh) {
        f32x4& a = (hh == 0) ? s0[0] : s0[1];
        f32x4& bb = (hh == 0) ? s1[0] : s1[1];
        float l = 0.f;
#pragma unroll
        for (int r = 0; r < 4; ++r) {
          float p0 = fast_exp2(a[r]); a[r] = p0; l += p0;
          float p1 = fast_exp2(bb[r]); bb[r] = p1; l += p1;
        }
        l_run[hh] += l;
        bf16x8 pv;
        pv[0] = (__bf16)a[0];  pv[1] = (__bf16)a[1];
        pv[2] = (__bf16)a[2];  pv[3] = (__bf16)a[3];
        pv[4] = (__bf16)bb[0]; pv[5] = (__bf16)bb[1];
        pv[6] = (__bf16)bb[2]; pv[7] = (__bf16)bb[3];
        pa[hh] = pv;
      }

      // PV: O[q][dd] += P * V ; vb shared across both halves
#pragma unroll
      for (int ntd = 0; ntd < 4; ++ntd) {
        const int cv = (((ks * 4 + quad) ^ f7)) * 8;   // V chunk ks*4+quad, swizzled
        bf16x8 vb = *(const bf16x8*)(sVc + (ntd * 16 + fr) * 128 + cv);
        o[0][ntd] = __builtin_amdgcn_mfma_f32_16x16x32_bf16(pa[0], vb, o[0][ntd], 0, 0, 0);
        o[1][ntd] = __builtin_amdgcn_mfma_f32_16x16x32_bf16(pa[1], vb, o[1][ntd], 0, 0, 0);
      }
    }

    if (kc < 7) __syncthreads();   // prefetch drained (vmcnt0) + all reads of cur done
  }

  // Denominator reduction via per-wave LDS scratch: lane(fr,quad) holds the
  // partial sum for q=fr over keys == quad*4+{0..3} (mod 16). Sum the 4 quads.
  red[wave][0][quad][fr] = l_run[0];
  red[wave][1][quad][fr] = l_run[1];
  __syncthreads();

#pragma unroll
  for (int hh = 0; hh < 2; ++hh) {
    float inv[4];
#pragma unroll
    for (int r = 0; r < 4; ++r) {
      const int ql = quad * 4 + r;   // q-within-16 of output row
      float d = red[wave][hh][0][ql] + red[wave][hh][1][ql] +
                red[wave][hh][2][ql] + red[wave][hh][3][ql];
      inv[r] = fast_rcp(d);
    }
#pragma unroll
    for (int ntd = 0; ntd < 4; ++ntd)
#pragma unroll
      for (int r = 0; r < 4; ++r) {
        const int row = q0 + hh * 64 + wave * 16 + quad * 4 + r;
        const int col = h * 64 + ntd * 16 + fr;
        Out[(size_t)(b * 2048 + row) * 1024 + col] = o[hh][ntd][r] * inv[r];
      }
  }
}

// ---------------- launch ----------------
extern "C" void kernel_launch(void* const* d_in, const int* in_sizes, int n_in,
                              void* d_out, int out_size, void* d_ws, size_t ws_size,
                              hipStream_t stream) {
  (void)in_sizes; (void)n_in; (void)out_size; (void)ws_size;
  const float* x   = (const float*)d_in[0];   // [4,2048,1024]
  const float* y   = (const float*)d_in[1];   // [4,1024,768]
  const int*   msk = (const int*)d_in[2];     // [4,2048]
  const float* Wq  = (const float*)d_in[3];   // [1024,1024]
  const float* Wkv = (const float*)d_in[4];   // [2048,768]
  float* out = (float*)d_out;                 // [4,2048,1024] f32

  char* ws = (char*)d_ws;
  const size_t MB = 1024 * 1024;
  u16* Xb   = (u16*)(ws + 0);        // 16 MB [8192][1024] mask-folded (dead after gemms)
  u16* Wqb  = (u16*)(ws + 16 * MB);  //  2 MB [1024][1024] * d^-0.5 * log2e
  u16* Yb   = (u16*)(ws + 18 * MB);  //  6 MB [4096][768]
  u16* Wkvb = (u16*)(ws + 24 * MB);  //  3 MB [2048][768]
  u16* Qb   = (u16*)(ws + 27 * MB);  // 16 MB [8192][1024]
  u16* KVb  = (u16*)(ws + 43 * MB);  // 16 MB [4096][2048]
  u16* Vtb  = (u16*)(ws + 59 * MB);  //  8 MB [4096][1024]  (high-water 67 MB)

  cvt_all<<<13824, 256, 0, stream>>>(x, Wq, y, Wkv, msk, Xb, Wqb, Yb, Wkvb);
  gemm_dual<<<1024, 256, 0, stream>>>(Xb, Wqb, Qb, Yb, Wkvb, KVb);
  transpose_v<<<dim3(64, 16), 256, 0, stream>>>(KVb, Vtb);
  attn_kernel<<<1024, 256, 0, stream>>>(Qb, KVb, Vtb, out);
}

// Round 9
// 180.503 us; speedup vs baseline: 1.0932x; 1.0516x over previous
//
#include <hip/hip_runtime.h>

typedef unsigned short u16;
typedef unsigned int u32;
typedef __attribute__((ext_vector_type(8))) __bf16 bf16x8;
typedef __attribute__((ext_vector_type(4))) float f32x4;

__device__ __forceinline__ u16 f2bf(float f) {
  unsigned u = __float_as_uint(f);
  u += 0x7FFFu + ((u >> 16) & 1u);   // round-to-nearest-even
  return (u16)(u >> 16);
}

__device__ __forceinline__ float fast_exp2(float x) { return __builtin_amdgcn_exp2f(x); }
__device__ __forceinline__ float fast_rcp(float x) { return __builtin_amdgcn_rcpf(x); }

// ---------------- merged f32 -> bf16 conversions (one dispatch) ----------------
// R9: 4 float4/thread, block = 1024 consecutive f4 (segment-uniform: all segment
// boundaries are multiples of 1024). Per-instruction coalesced (j = jb + u*256).
// blocks: [0,2048)=x  [2048,2304)=Wq  [2304,3072)=y  [3072,3456)=Wkv
__global__ void cvt_all(const float* __restrict__ x, const float* __restrict__ Wq,
                        const float* __restrict__ y, const float* __restrict__ Wkv,
                        const int* __restrict__ mask,
                        u16* __restrict__ Xb, u16* __restrict__ Wqb,
                        u16* __restrict__ Yb, u16* __restrict__ Wkvb) {
  const int t = threadIdx.x;
  const int blk = blockIdx.x;
  const float4* src;
  u16* dst;
  int jb;
  float sc;
  bool m0 = false;
  if (blk < 2048) {
    src = (const float4*)x; dst = Xb; jb = blk * 1024 + t; m0 = true; sc = 1.0f;
  } else if (blk < 2304) {
    src = (const float4*)Wq; dst = Wqb; jb = (blk - 2048) * 1024 + t;
    sc = 0.18033688f;  // d^-0.5 * log2(e): softmax exp via single v_exp_f32 (base-2)
  } else if (blk < 3072) {
    src = (const float4*)y; dst = Yb; jb = (blk - 2304) * 1024 + t; sc = 1.0f;
  } else {
    src = (const float4*)Wkv; dst = Wkvb; jb = (blk - 3072) * 1024 + t; sc = 1.0f;
  }
#pragma unroll
  for (int u = 0; u < 4; ++u) {
    const int j = jb + u * 256;
    float s = sc;
    if (m0) s = (mask[j >> 8] != 0) ? 1.0f : 0.0f;  // masked q-rows -> Q=0 -> uniform softmax
    float4 v = src[j];
    ushort4 o;
    o.x = f2bf(v.x * s);
    o.y = f2bf(v.y * s);
    o.z = f2bf(v.z * s);
    o.w = f2bf(v.w * s);
    ((ushort4*)dst)[j] = o;
  }
}

// ---------------- merged dual bf16 GEMM + fused V-transpose epilogue ----------------
// m97 tile geometry (128x128, BK=32, 4 waves, 16x16x32 MFMA, gload_lds w=16),
// R6/R8-proven transport (2-buffer LDS, depth-1 prefetch, one __syncthreads/K-step),
// R7-proven XCD tile remap (same-bx == mod 8 -> same XCD L2; FETCH 94->35MB).
// R9: V-half blocks (by>=8 of KV gemm) write acc -> LDS tile -> Vt directly
// (transposed + key-perm, coalesced u32 stores), replacing the transpose_v kernel.
// K-half / Q blocks keep the plain C-write.
__global__ __launch_bounds__(256) void gemm_dual(
    const u16* __restrict__ Aq, const u16* __restrict__ Bq, u16* __restrict__ Cq,
    const u16* __restrict__ Akv, const u16* __restrict__ Bkv, u16* __restrict__ Ckv,
    u16* __restrict__ Vt) {
  // staging: sA = smem[0..8192), sB = smem[8192..16384) (u16 units, 2 bufs each)
  // epilogue (V-blocks only, after barrier): T[128][136] = smem[0..17408)
  __shared__ __align__(16) u16 smem[17408];
  u16* sA = smem;
  u16* sB = smem + 8192;
  const int t = threadIdx.x;
  const int wave = t >> 6;
  const int lane = t & 63;
  const int wm = (wave >> 1) * 64;
  const int wn = (wave & 1) * 64;
  const int fr = lane & 15;
  const int quad = lane >> 4;
  const int fk = quad * 8;
  const int sr = lane >> 2;
  const int sc = (lane & 3) * 8;

  const u16 *A, *B;
  u16* C;
  int N, K, bx, by;
  const int blk = blockIdx.x;
  if (blk < 512) {
    A = Aq; B = Bq; C = Cq; N = 1024; K = 1024;
    by = blk >> 6; bx = blk & 63;           // 64 x 8 tiles, M=8192; same bx -> same XCD
  } else {
    A = Akv; B = Bkv; C = Ckv; N = 2048; K = 768;
    const int id = blk - 512;
    by = id >> 5; bx = id & 31;             // 32 x 16 tiles, M=4096; same bx -> same XCD
  }

  f32x4 acc[4][4];
  const f32x4 z4 = {0.f, 0.f, 0.f, 0.f};
#pragma unroll
  for (int i = 0; i < 4; ++i)
#pragma unroll
    for (int j = 0; j < 4; ++j) acc[i][j] = z4;

  const u16* Abase = A + (size_t)bx * 128 * K;
  const u16* Bbase = B + (size_t)by * 128 * K;

  auto stage = [&](int k0, u16* dA, u16* dB) {
#pragma unroll
    for (int q = 0; q < 2; ++q) {
      const int chunk = wave * 2 + q;
      const int row = chunk * 16 + sr;
      __builtin_amdgcn_global_load_lds(
          (__attribute__((address_space(1))) void*)(Abase + (size_t)row * K + k0 + sc),
          (__attribute__((address_space(3))) void*)(dA + chunk * 512), 16, 0, 0);
      __builtin_amdgcn_global_load_lds(
          (__attribute__((address_space(1))) void*)(Bbase + (size_t)row * K + k0 + sc),
          (__attribute__((address_space(3))) void*)(dB + chunk * 512), 16, 0, 0);
    }
  };

  stage(0, sA, sB);
  __syncthreads();   // vmcnt drained before barrier -> buf0 ready

  int it = 0;
  for (int k0 = 0; k0 < K; k0 += 32, ++it) {
    u16* cA = sA + (it & 1) * 4096;
    u16* cB = sB + (it & 1) * 4096;
    // prefetch next K-step into the other buffer; completes under compute
    if (k0 + 32 < K) stage(k0 + 32, sA + ((it + 1) & 1) * 4096, sB + ((it + 1) & 1) * 4096);

    bf16x8 af[4], bfv[4];
#pragma unroll
    for (int i = 0; i < 4; ++i)
      af[i] = *(const bf16x8*)(cA + (wm + i * 16 + fr) * 32 + fk);
#pragma unroll
    for (int j = 0; j < 4; ++j)
      bfv[j] = *(const bf16x8*)(cB + (wn + j * 16 + fr) * 32 + fk);
#pragma unroll
    for (int i = 0; i < 4; ++i)
#pragma unroll
      for (int j = 0; j < 4; ++j)
        acc[i][j] = __builtin_amdgcn_mfma_f32_16x16x32_bf16(af[i], bfv[j], acc[i][j], 0, 0, 0);

    // one barrier per K-step: prefetch drained (vmcnt0) + all reads of cur done
    if (k0 + 32 < K) __syncthreads();
  }

  if (blk >= 512 && by >= 8) {
    // ---- fused V-transpose epilogue (block-uniform branch; barriers safe) ----
    // This block computed V values: C[row = b*1024+n2][col = 1024+hd],
    // b = bx>>3, n2 = (bx&7)*128 + row_local, hd = (by-8)*128 + col_local,
    // h = hd>>6, dd = hd&63. Vt[( (b*16+h)*64+dd )*1024 + (n2>>6)*64 + perm(n2&63)]
    // with perm(m) = (m&32)|(((m>>2)&3)<<3)|(((m>>4)&1)<<2)|(m&3)  (== transpose_v).
    __syncthreads();   // all waves done with staging LDS
    // store acc transposed: T[col_local][row_local], stride 136 (u32-even, bank-spread)
#pragma unroll
    for (int i = 0; i < 4; ++i)
#pragma unroll
      for (int j = 0; j < 4; ++j) {
        ushort4 o;
        o.x = f2bf(acc[i][j][0]);
        o.y = f2bf(acc[i][j][1]);
        o.z = f2bf(acc[i][j][2]);
        o.w = f2bf(acc[i][j][3]);
        *(ushort4*)(smem + (wn + j * 16 + fr) * 136 + wm + i * 16 + quad * 4) = o;
      }
    __syncthreads();
    // write out: output position pairs (pe, pe+1) <- keys (inv(pe), inv(pe)+1)
    // inv(p) = (p&32)|(p&3)|(((p>>3)&3)<<2)|(((p>>2)&1)<<4); p even -> inv even.
    const int b = bx >> 3;
#pragma unroll
    for (int i2 = 0; i2 < 32; ++i2) {
      const int flat = i2 * 256 + t;
      const int hdl = flat >> 6;          // 0..127 (wave-uniform)
      const int pp = flat & 63;           // lane
      const int gg = pp >> 5;             // which 64-key group
      const int pe = (pp & 31) * 2;       // even output position within group
      const int m = (pe & 32) | (pe & 3) | (((pe >> 3) & 3) << 2) | (((pe >> 2) & 1) << 4);
      const u32 val = *(const u32*)(smem + hdl * 136 + gg * 64 + m);
      const int h = (by - 8) * 2 + (hdl >> 6);
      const int dd = hdl & 63;
      *(u32*)(Vt + (size_t)((b * 16 + h) * 64 + dd) * 1024 +
              (bx & 7) * 128 + gg * 64 + pe) = val;
    }
  } else {
    // ---- plain C-write (Q blocks and K-half blocks) ----
#pragma unroll
    for (int i = 0; i < 4; ++i)
#pragma unroll
      for (int j = 0; j < 4; ++j)
#pragma unroll
        for (int r = 0; r < 4; ++r) {
          const int row = bx * 128 + wm + i * 16 + quad * 4 + r;
          const int col = by * 128 + wn + j * 16 + fr;
          C[(size_t)row * N + col] = f2bf(acc[i][j][r]);
        }
  }
}

// ---------------- fused flash attention (in-register P + gload_lds double-buffer) ----------------
// R5 (passed, 45.5us): swapped QK^T in-register P, fixed-max softmax, double-buffered
// LDS via global_load_lds, one barrier per kc, both-sides XOR chunk-swizzle.
// UNCHANGED (proven).
__global__ __launch_bounds__(256, 2) void attn_kernel(
    const u16* __restrict__ Q, const u16* __restrict__ KV,
    const u16* __restrict__ Vt, float* __restrict__ Out) {
  __shared__ __align__(16) u16 sK[2 * 128 * 64];   // [buf][key][dd], swizzled chunks
  __shared__ __align__(16) u16 sV[2 * 64 * 128];   // [buf][dd][perm key], swizzled chunks
  __shared__ float red[4][2][4][16];               // [wave][hh][quad][fr] partial denoms

  const int t = threadIdx.x;
  const int wave = t >> 6;
  const int lane = t & 63;
  // XCD swizzle: all 16 q-tiles of one (b,h) are == mod 64 -> same XCD L2.
  const int g = blockIdx.x & 63;
  const int qt = blockIdx.x >> 6;   // 0..15
  const int b = g >> 4;
  const int h = g & 15;
  const int q0 = qt * 128;
  const int fr = lane & 15;
  const int quad = lane >> 4;
  const int l3 = lane >> 3, l7 = lane & 7;     // K staging decomposition
  const int l4 = lane >> 4, l15 = lane & 15;   // V staging decomposition

  // Q fragments for both halves (kc-invariant, from global once).
  const u16* qbase = Q + (size_t)(b * 2048 + q0 + wave * 16 + fr) * 1024 + h * 64 + quad * 8;
  bf16x8 qa[2][2];
  qa[0][0] = *(const bf16x8*)(qbase);
  qa[0][1] = *(const bf16x8*)(qbase + 32);
  qa[1][0] = *(const bf16x8*)(qbase + (size_t)64 * 1024);
  qa[1][1] = *(const bf16x8*)(qbase + (size_t)64 * 1024 + 32);

  // ---- staging: 16 K-loads (8 rows x 128B each) + 16 V-loads (4 rows x 256B each)
  // K: load j covers rows 8j..8j+7; lane l -> row 8j+l3, stores LDS chunk l7,
  //    sources global col16 = l7 ^ l3 (so LDS chunk c holds col c^(row&7)).
  // V: load j covers rows 4j..4j+3; lane l -> row 4j+l4, stores LDS chunk l15,
  //    sources global chunk = l15 ^ (4*(j&1)+l4).
  const int kq = (l7 ^ l3) * 8;                  // K src col offset (u16)
  auto stage = [&](int kcn, u16* dK, u16* dV) {
#pragma unroll
    for (int i = 0; i < 4; ++i) {
      const int j = wave * 4 + i;
      const u16* ksrc = KV + (size_t)(b * 1024 + kcn * 128 + 8 * j + l3) * 2048 + h * 64 + kq;
      __builtin_amdgcn_global_load_lds(
          (__attribute__((address_space(1))) void*)ksrc,
          (__attribute__((address_space(3))) void*)(dK + j * 512), 16, 0, 0);
      const int vq = (l15 ^ ((i & 1) * 4 + l4)) * 8;   // V src chunk offset (u16)
      const u16* vsrc = Vt + (size_t)((b * 16 + h) * 64 + 4 * j + l4) * 1024 + kcn * 128 + vq;
      __builtin_amdgcn_global_load_lds(
          (__attribute__((address_space(1))) void*)vsrc,
          (__attribute__((address_space(3))) void*)(dV + j * 512), 16, 0, 0);
    }
  };

  stage(0, sK, sV);
  __syncthreads();   // compiler drains vmcnt before the barrier

  const f32x4 z4 = {0.f, 0.f, 0.f, 0.f};
  f32x4 o[2][4];
  float l_run[2] = {0.f, 0.f};
#pragma unroll
  for (int hh = 0; hh < 2; ++hh)
#pragma unroll
    for (int nt = 0; nt < 4; ++nt) o[hh][nt] = z4;

  // swizzled read chunk offsets (u16): chunk q of row r lives at (q^(r&7))*8; r&7==fr&7
  const int f7 = fr & 7;
  const int ck0 = (quad ^ f7) * 8;          // K chunk quad
  const int ck1 = ((quad ^ 4) ^ f7) * 8;    // K chunk quad+4

  for (int kc = 0; kc < 8; ++kc) {
    const u16* sKc = sK + (kc & 1) * 8192;
    const u16* sVc = sV + (kc & 1) * 8192;
    // issue next chunk's prefetch into the other buffer (completes under compute)
    if (kc < 7) stage(kc + 1, sK + ((kc + 1) & 1) * 8192, sV + ((kc + 1) & 1) * 8192);

    // Streamed per 32-key slice: QK^T -> exp2 -> pack -> PV (fixed-max, no S matrix).
#pragma unroll
    for (int ks = 0; ks < 4; ++ks) {
      f32x4 s0[2], s1[2];   // [hh], nt=2ks and 2ks+1
      {
        const u16* kb = sKc + ((2 * ks) * 16 + fr) * 64;
        bf16x8 k0 = *(const bf16x8*)(kb + ck0);
        bf16x8 k1 = *(const bf16x8*)(kb + ck1);
        s0[0] = __builtin_amdgcn_mfma_f32_16x16x32_bf16(k0, qa[0][0], z4, 0, 0, 0);
        s0[0] = __builtin_amdgcn_mfma_f32_16x16x32_bf16(k1, qa[0][1], s0[0], 0, 0, 0);
        s0[1] = __builtin_amdgcn_mfma_f32_16x16x32_bf16(k0, qa[1][0], z4, 0, 0, 0);
        s0[1] = __builtin_amdgcn_mfma_f32_16x16x32_bf16(k1, qa[1][1], s0[1], 0, 0, 0);
      }
      {
        const u16* kb = sKc + ((2 * ks + 1) * 16 + fr) * 64;
        bf16x8 k0 = *(const bf16x8*)(kb + ck0);
        bf16x8 k1 = *(const bf16x8*)(kb + ck1);
        s1[0] = __builtin_amdgcn_mfma_f32_16x16x32_bf16(k0, qa[0][0], z4, 0, 0, 0);
        s1[0] = __builtin_amdgcn_mfma_f32_16x16x32_bf16(k1, qa[0][1], s1[0], 0, 0, 0);
        s1[1] = __builtin_amdgcn_mfma_f32_16x16x32_bf16(k0, qa[1][0], z4, 0, 0, 0);
        s1[1] = __builtin_amdgcn_mfma_f32_16x16x32_bf16(k1, qa[1][1], s1[1], 0, 0, 0);
      }

      // P = 2^s in-register; pack into PV A-fragment (key order matches Vt's sigma):
      // elem j=0..3 <- s0[r] (keys quad*4+r), j=4..7 <- s1[r] (keys 16+quad*4+r).
      bf16x8 pa[2];
#pragma unroll
      for (int hh = 0; hh < 2; ++hh) {
        f32x4& a = (hh == 0) ? s0[0] : s0[1];
        f32x4& bb = (hh == 0) ? s1[0] : s1[1];
        float l = 0.f;
#pragma unroll
        for (int r = 0; r < 4; ++r) {
          float p0 = fast_exp2(a[r]); a[r] = p0; l += p0;
          float p1 = fast_exp2(bb[r]); bb[r] = p1; l += p1;
        }
        l_run[hh] += l;
        bf16x8 pv;
        pv[0] = (__bf16)a[0];  pv[1] = (__bf16)a[1];
        pv[2] = (__bf16)a[2];  pv[3] = (__bf16)a[3];
        pv[4] = (__bf16)bb[0]; pv[5] = (__bf16)bb[1];
        pv[6] = (__bf16)bb[2]; pv[7] = (__bf16)bb[3];
        pa[hh] = pv;
      }

      // PV: O[q][dd] += P * V ; vb shared across both halves
#pragma unroll
      for (int ntd = 0; ntd < 4; ++ntd) {
        const int cv = (((ks * 4 + quad) ^ f7)) * 8;   // V chunk ks*4+quad, swizzled
        bf16x8 vb = *(const bf16x8*)(sVc + (ntd * 16 + fr) * 128 + cv);
        o[0][ntd] = __builtin_amdgcn_mfma_f32_16x16x32_bf16(pa[0], vb, o[0][ntd], 0, 0, 0);
        o[1][ntd] = __builtin_amdgcn_mfma_f32_16x16x32_bf16(pa[1], vb, o[1][ntd], 0, 0, 0);
      }
    }

    if (kc < 7) __syncthreads();   // prefetch drained (vmcnt0) + all reads of cur done
  }

  // Denominator reduction via per-wave LDS scratch: lane(fr,quad) holds the
  // partial sum for q=fr over keys == quad*4+{0..3} (mod 16). Sum the 4 quads.
  red[wave][0][quad][fr] = l_run[0];
  red[wave][1][quad][fr] = l_run[1];
  __syncthreads();

#pragma unroll
  for (int hh = 0; hh < 2; ++hh) {
    float inv[4];
#pragma unroll
    for (int r = 0; r < 4; ++r) {
      const int ql = quad * 4 + r;   // q-within-16 of output row
      float d = red[wave][hh][0][ql] + red[wave][hh][1][ql] +
                red[wave][hh][2][ql] + red[wave][hh][3][ql];
      inv[r] = fast_rcp(d);
    }
#pragma unroll
    for (int ntd = 0; ntd < 4; ++ntd)
#pragma unroll
      for (int r = 0; r < 4; ++r) {
        const int row = q0 + hh * 64 + wave * 16 + quad * 4 + r;
        const int col = h * 64 + ntd * 16 + fr;
        Out[(size_t)(b * 2048 + row) * 1024 + col] = o[hh][ntd][r] * inv[r];
      }
  }
}

// ---------------- launch ----------------
extern "C" void kernel_launch(void* const* d_in, const int* in_sizes, int n_in,
                              void* d_out, int out_size, void* d_ws, size_t ws_size,
                              hipStream_t stream) {
  (void)in_sizes; (void)n_in; (void)out_size; (void)ws_size;
  const float* x   = (const float*)d_in[0];   // [4,2048,1024]
  const float* y   = (const float*)d_in[1];   // [4,1024,768]
  const int*   msk = (const int*)d_in[2];     // [4,2048]
  const float* Wq  = (const float*)d_in[3];   // [1024,1024]
  const float* Wkv = (const float*)d_in[4];   // [2048,768]
  float* out = (float*)d_out;                 // [4,2048,1024] f32

  char* ws = (char*)d_ws;
  const size_t MB = 1024 * 1024;
  u16* Xb   = (u16*)(ws + 0);        // 16 MB [8192][1024] mask-folded
  u16* Wqb  = (u16*)(ws + 16 * MB);  //  2 MB [1024][1024] * d^-0.5 * log2e
  u16* Yb   = (u16*)(ws + 18 * MB);  //  6 MB [4096][768]
  u16* Wkvb = (u16*)(ws + 24 * MB);  //  3 MB [2048][768]
  u16* Qb   = (u16*)(ws + 27 * MB);  // 16 MB [8192][1024]
  u16* KVb  = (u16*)(ws + 43 * MB);  // 16 MB [4096][2048] (only K half written/used)
  u16* Vtb  = (u16*)(ws + 59 * MB);  //  8 MB [4096][1024]  (high-water 67 MB)

  cvt_all<<<3456, 256, 0, stream>>>(x, Wq, y, Wkv, msk, Xb, Wqb, Yb, Wkvb);
  gemm_dual<<<1024, 256, 0, stream>>>(Xb, Wqb, Qb, Yb, Wkvb, KVb, Vtb);
  attn_kernel<<<1024, 256, 0, stream>>>(Qb, KVb, Vtb, out);
}

// Round 10
// 179.224 us; speedup vs baseline: 1.1010x; 1.0071x over previous
//
#include <hip/hip_runtime.h>

typedef unsigned short u16;
typedef unsigned int u32;
typedef __attribute__((ext_vector_type(8))) __bf16 bf16x8;
typedef __attribute__((ext_vector_type(4))) float f32x4;

__device__ __forceinline__ u16 f2bf(float f) {
  unsigned u = __float_as_uint(f);
  u += 0x7FFFu + ((u >> 16) & 1u);   // round-to-nearest-even
  return (u16)(u >> 16);
}

__device__ __forceinline__ float fast_exp2(float x) { return __builtin_amdgcn_exp2f(x); }
__device__ __forceinline__ float fast_rcp(float x) { return __builtin_amdgcn_rcpf(x); }

// ---------------- merged f32 -> bf16 conversions (one dispatch) ----------------
// 4 float4/thread, block = 1024 consecutive f4 (segment-uniform boundaries).
// blocks: [0,2048)=x  [2048,2304)=Wq  [2304,3072)=y  [3072,3456)=Wkv
__global__ void cvt_all(const float* __restrict__ x, const float* __restrict__ Wq,
                        const float* __restrict__ y, const float* __restrict__ Wkv,
                        const int* __restrict__ mask,
                        u16* __restrict__ Xb, u16* __restrict__ Wqb,
                        u16* __restrict__ Yb, u16* __restrict__ Wkvb) {
  const int t = threadIdx.x;
  const int blk = blockIdx.x;
  const float4* src;
  u16* dst;
  int jb;
  float sc;
  bool m0 = false;
  if (blk < 2048) {
    src = (const float4*)x; dst = Xb; jb = blk * 1024 + t; m0 = true; sc = 1.0f;
  } else if (blk < 2304) {
    src = (const float4*)Wq; dst = Wqb; jb = (blk - 2048) * 1024 + t;
    sc = 0.18033688f;  // d^-0.5 * log2(e): softmax exp via single v_exp_f32 (base-2)
  } else if (blk < 3072) {
    src = (const float4*)y; dst = Yb; jb = (blk - 2304) * 1024 + t; sc = 1.0f;
  } else {
    src = (const float4*)Wkv; dst = Wkvb; jb = (blk - 3072) * 1024 + t; sc = 1.0f;
  }
#pragma unroll
  for (int u = 0; u < 4; ++u) {
    const int j = jb + u * 256;
    float s = sc;
    if (m0) s = (mask[j >> 8] != 0) ? 1.0f : 0.0f;  // masked q-rows -> Q=0 -> uniform softmax
    float4 v = src[j];
    ushort4 o;
    o.x = f2bf(v.x * s);
    o.y = f2bf(v.y * s);
    o.z = f2bf(v.z * s);
    o.w = f2bf(v.w * s);
    ((ushort4*)dst)[j] = o;
  }
}

// ---------------- merged dual bf16 GEMM + fused V-transpose epilogue ----------------
// m97 tile geometry (128x128, BK=32, 4 waves, 16x16x32 MFMA, gload_lds w=16),
// R6/R8-proven transport (2-buffer LDS, depth-1 prefetch, one __syncthreads/K-step),
// R7-proven XCD tile remap (same-bx == mod 8 -> same XCD L2; FETCH 94->35MB).
// R9-proven fused V-transpose epilogue (V-half blocks write Vt directly).
// UNCHANGED this round.
__global__ __launch_bounds__(256) void gemm_dual(
    const u16* __restrict__ Aq, const u16* __restrict__ Bq, u16* __restrict__ Cq,
    const u16* __restrict__ Akv, const u16* __restrict__ Bkv, u16* __restrict__ Ckv,
    u16* __restrict__ Vt) {
  // staging: sA = smem[0..8192), sB = smem[8192..16384) (u16 units, 2 bufs each)
  // epilogue (V-blocks only, after barrier): T[128][136] = smem[0..17408)
  __shared__ __align__(16) u16 smem[17408];
  u16* sA = smem;
  u16* sB = smem + 8192;
  const int t = threadIdx.x;
  const int wave = t >> 6;
  const int lane = t & 63;
  const int wm = (wave >> 1) * 64;
  const int wn = (wave & 1) * 64;
  const int fr = lane & 15;
  const int quad = lane >> 4;
  const int fk = quad * 8;
  const int sr = lane >> 2;
  const int sc = (lane & 3) * 8;

  const u16 *A, *B;
  u16* C;
  int N, K, bx, by;
  const int blk = blockIdx.x;
  if (blk < 512) {
    A = Aq; B = Bq; C = Cq; N = 1024; K = 1024;
    by = blk >> 6; bx = blk & 63;           // 64 x 8 tiles, M=8192; same bx -> same XCD
  } else {
    A = Akv; B = Bkv; C = Ckv; N = 2048; K = 768;
    const int id = blk - 512;
    by = id >> 5; bx = id & 31;             // 32 x 16 tiles, M=4096; same bx -> same XCD
  }

  f32x4 acc[4][4];
  const f32x4 z4 = {0.f, 0.f, 0.f, 0.f};
#pragma unroll
  for (int i = 0; i < 4; ++i)
#pragma unroll
    for (int j = 0; j < 4; ++j) acc[i][j] = z4;

  const u16* Abase = A + (size_t)bx * 128 * K;
  const u16* Bbase = B + (size_t)by * 128 * K;

  auto stage = [&](int k0, u16* dA, u16* dB) {
#pragma unroll
    for (int q = 0; q < 2; ++q) {
      const int chunk = wave * 2 + q;
      const int row = chunk * 16 + sr;
      __builtin_amdgcn_global_load_lds(
          (__attribute__((address_space(1))) void*)(Abase + (size_t)row * K + k0 + sc),
          (__attribute__((address_space(3))) void*)(dA + chunk * 512), 16, 0, 0);
      __builtin_amdgcn_global_load_lds(
          (__attribute__((address_space(1))) void*)(Bbase + (size_t)row * K + k0 + sc),
          (__attribute__((address_space(3))) void*)(dB + chunk * 512), 16, 0, 0);
    }
  };

  stage(0, sA, sB);
  __syncthreads();   // vmcnt drained before barrier -> buf0 ready

  int it = 0;
  for (int k0 = 0; k0 < K; k0 += 32, ++it) {
    u16* cA = sA + (it & 1) * 4096;
    u16* cB = sB + (it & 1) * 4096;
    // prefetch next K-step into the other buffer; completes under compute
    if (k0 + 32 < K) stage(k0 + 32, sA + ((it + 1) & 1) * 4096, sB + ((it + 1) & 1) * 4096);

    bf16x8 af[4], bfv[4];
#pragma unroll
    for (int i = 0; i < 4; ++i)
      af[i] = *(const bf16x8*)(cA + (wm + i * 16 + fr) * 32 + fk);
#pragma unroll
    for (int j = 0; j < 4; ++j)
      bfv[j] = *(const bf16x8*)(cB + (wn + j * 16 + fr) * 32 + fk);
#pragma unroll
    for (int i = 0; i < 4; ++i)
#pragma unroll
      for (int j = 0; j < 4; ++j)
        acc[i][j] = __builtin_amdgcn_mfma_f32_16x16x32_bf16(af[i], bfv[j], acc[i][j], 0, 0, 0);

    // one barrier per K-step: prefetch drained (vmcnt0) + all reads of cur done
    if (k0 + 32 < K) __syncthreads();
  }

  if (blk >= 512 && by >= 8) {
    // ---- fused V-transpose epilogue (block-uniform branch; barriers safe) ----
    __syncthreads();   // all waves done with staging LDS
#pragma unroll
    for (int i = 0; i < 4; ++i)
#pragma unroll
      for (int j = 0; j < 4; ++j) {
        ushort4 o;
        o.x = f2bf(acc[i][j][0]);
        o.y = f2bf(acc[i][j][1]);
        o.z = f2bf(acc[i][j][2]);
        o.w = f2bf(acc[i][j][3]);
        *(ushort4*)(smem + (wn + j * 16 + fr) * 136 + wm + i * 16 + quad * 4) = o;
      }
    __syncthreads();
    // output position pairs (pe, pe+1) <- keys (inv(pe), inv(pe)+1)
    // inv(p) = (p&32)|(p&3)|(((p>>3)&3)<<2)|(((p>>2)&1)<<4); p even -> inv even.
    const int b = bx >> 3;
#pragma unroll
    for (int i2 = 0; i2 < 32; ++i2) {
      const int flat = i2 * 256 + t;
      const int hdl = flat >> 6;          // 0..127 (wave-uniform)
      const int pp = flat & 63;           // lane
      const int gg = pp >> 5;             // which 64-key group
      const int pe = (pp & 31) * 2;       // even output position within group
      const int m = (pe & 32) | (pe & 3) | (((pe >> 3) & 3) << 2) | (((pe >> 2) & 1) << 4);
      const u32 val = *(const u32*)(smem + hdl * 136 + gg * 64 + m);
      const int h = (by - 8) * 2 + (hdl >> 6);
      const int dd = hdl & 63;
      *(u32*)(Vt + (size_t)((b * 16 + h) * 64 + dd) * 1024 +
              (bx & 7) * 128 + gg * 64 + pe) = val;
    }
  } else {
    // ---- plain C-write (Q blocks and K-half blocks) ----
#pragma unroll
    for (int i = 0; i < 4; ++i)
#pragma unroll
      for (int j = 0; j < 4; ++j)
#pragma unroll
        for (int r = 0; r < 4; ++r) {
          const int row = bx * 128 + wm + i * 16 + quad * 4 + r;
          const int col = by * 128 + wn + j * 16 + fr;
          C[(size_t)row * N + col] = f2bf(acc[i][j][r]);
        }
  }
}

// ---------------- fused flash attention (in-register P, KVBLK=64, 4 blocks/CU) ----------------
// R5-proven math (swapped QK^T in-register P, fixed-max softmax, both-sides XOR
// swizzle, gload_lds double-buffer). R10: KVBLK 128 -> 64. LDS 67584 -> 34816 B
// -> 4 blocks/CU (was 2); grid 1024 fully co-resident, 4 waves/SIMD hide the
// doubled-but-cheaper barriers. Staging invariant unchanged: LDS chunk c of row
// r holds source chunk c^(r&7); reads XOR f7. V staging now same form as K
// (row = 8j+l3, src chunk = l7^l3). Vt's 32-key-group sigma is chunk-agnostic.
__global__ __launch_bounds__(256, 4) void attn_kernel(
    const u16* __restrict__ Q, const u16* __restrict__ KV,
    const u16* __restrict__ Vt, float* __restrict__ Out) {
  __shared__ __align__(16) u16 sK[2 * 64 * 64];    // [buf][key][dd], swizzled chunks
  __shared__ __align__(16) u16 sV[2 * 64 * 64];    // [buf][dd][perm key], swizzled chunks
  __shared__ float red[4][2][4][16];               // [wave][hh][quad][fr] partial denoms

  const int t = threadIdx.x;
  const int wave = t >> 6;
  const int lane = t & 63;
  // XCD swizzle: all 16 q-tiles of one (b,h) are == mod 64 -> same XCD L2.
  const int g = blockIdx.x & 63;
  const int qt = blockIdx.x >> 6;   // 0..15
  const int b = g >> 4;
  const int h = g & 15;
  const int q0 = qt * 128;
  const int fr = lane & 15;
  const int quad = lane >> 4;
  const int l3 = lane >> 3, l7 = lane & 7;     // staging decomposition (K and V)

  // Q fragments for both halves (kc-invariant, from global once).
  const u16* qbase = Q + (size_t)(b * 2048 + q0 + wave * 16 + fr) * 1024 + h * 64 + quad * 8;
  bf16x8 qa[2][2];
  qa[0][0] = *(const bf16x8*)(qbase);
  qa[0][1] = *(const bf16x8*)(qbase + 32);
  qa[1][0] = *(const bf16x8*)(qbase + (size_t)64 * 1024);
  qa[1][1] = *(const bf16x8*)(qbase + (size_t)64 * 1024 + 32);

  // ---- staging per 64-key chunk: 8 K-loads + 8 V-loads (2+2 per wave)
  // K: load j covers key-rows 8j..8j+7; lane l -> row 8j+l3, LDS chunk l7,
  //    src col16 = l7^l3  (LDS chunk c of row r holds src chunk c^(r&7)).
  // V: load j covers dd-rows 8j..8j+7; identical decomposition over Vt rows.
  const int sq = (l7 ^ l3) * 8;                  // src chunk offset (u16), K and V
  auto stage = [&](int kcn, u16* dK, u16* dV) {
#pragma unroll
    for (int i = 0; i < 2; ++i) {
      const int j = wave * 2 + i;
      const u16* ksrc = KV + (size_t)(b * 1024 + kcn * 64 + 8 * j + l3) * 2048 + h * 64 + sq;
      __builtin_amdgcn_global_load_lds(
          (__attribute__((address_space(1))) void*)ksrc,
          (__attribute__((address_space(3))) void*)(dK + j * 512), 16, 0, 0);
      const u16* vsrc = Vt + (size_t)((b * 16 + h) * 64 + 8 * j + l3) * 1024 + kcn * 64 + sq;
      __builtin_amdgcn_global_load_lds(
          (__attribute__((address_space(1))) void*)vsrc,
          (__attribute__((address_space(3))) void*)(dV + j * 512), 16, 0, 0);
    }
  };

  stage(0, sK, sV);
  __syncthreads();   // compiler drains vmcnt before the barrier

  const f32x4 z4 = {0.f, 0.f, 0.f, 0.f};
  f32x4 o[2][4];
  float l_run[2] = {0.f, 0.f};
#pragma unroll
  for (int hh = 0; hh < 2; ++hh)
#pragma unroll
    for (int nt = 0; nt < 4; ++nt) o[hh][nt] = z4;

  // swizzled read chunk offsets (u16): chunk q of row r lives at (q^(r&7))*8; r&7==fr&7
  const int f7 = fr & 7;
  const int ck0 = (quad ^ f7) * 8;          // K chunk quad
  const int ck1 = ((quad ^ 4) ^ f7) * 8;    // K chunk quad+4

  for (int kc = 0; kc < 16; ++kc) {
    const u16* sKc = sK + (kc & 1) * 4096;
    const u16* sVc = sV + (kc & 1) * 4096;
    // issue next chunk's prefetch into the other buffer (completes under compute)
    if (kc < 15) stage(kc + 1, sK + ((kc + 1) & 1) * 4096, sV + ((kc + 1) & 1) * 4096);

    // Streamed per 32-key slice: QK^T -> exp2 -> pack -> PV (fixed-max, no S matrix).
#pragma unroll
    for (int ks = 0; ks < 2; ++ks) {
      f32x4 s0[2], s1[2];   // [hh], nt=2ks and 2ks+1
      {
        const u16* kb = sKc + ((2 * ks) * 16 + fr) * 64;
        bf16x8 k0 = *(const bf16x8*)(kb + ck0);
        bf16x8 k1 = *(const bf16x8*)(kb + ck1);
        s0[0] = __builtin_amdgcn_mfma_f32_16x16x32_bf16(k0, qa[0][0], z4, 0, 0, 0);
        s0[0] = __builtin_amdgcn_mfma_f32_16x16x32_bf16(k1, qa[0][1], s0[0], 0, 0, 0);
        s0[1] = __builtin_amdgcn_mfma_f32_16x16x32_bf16(k0, qa[1][0], z4, 0, 0, 0);
        s0[1] = __builtin_amdgcn_mfma_f32_16x16x32_bf16(k1, qa[1][1], s0[1], 0, 0, 0);
      }
      {
        const u16* kb = sKc + ((2 * ks + 1) * 16 + fr) * 64;
        bf16x8 k0 = *(const bf16x8*)(kb + ck0);
        bf16x8 k1 = *(const bf16x8*)(kb + ck1);
        s1[0] = __builtin_amdgcn_mfma_f32_16x16x32_bf16(k0, qa[0][0], z4, 0, 0, 0);
        s1[0] = __builtin_amdgcn_mfma_f32_16x16x32_bf16(k1, qa[0][1], s1[0], 0, 0, 0);
        s1[1] = __builtin_amdgcn_mfma_f32_16x16x32_bf16(k0, qa[1][0], z4, 0, 0, 0);
        s1[1] = __builtin_amdgcn_mfma_f32_16x16x32_bf16(k1, qa[1][1], s1[1], 0, 0, 0);
      }

      // P = 2^s in-register; pack into PV A-fragment (key order matches Vt's sigma):
      // elem j=0..3 <- s0[r] (keys 32ks+quad*4+r), j=4..7 <- s1[r] (keys 32ks+16+quad*4+r).
      bf16x8 pa[2];
#pragma unroll
      for (int hh = 0; hh < 2; ++hh) {
        f32x4& a = (hh == 0) ? s0[0] : s0[1];
        f32x4& bb = (hh == 0) ? s1[0] : s1[1];
        float l = 0.f;
#pragma unroll
        for (int r = 0; r < 4; ++r) {
          float p0 = fast_exp2(a[r]); a[r] = p0; l += p0;
          float p1 = fast_exp2(bb[r]); bb[r] = p1; l += p1;
        }
        l_run[hh] += l;
        bf16x8 pv;
        pv[0] = (__bf16)a[0];  pv[1] = (__bf16)a[1];
        pv[2] = (__bf16)a[2];  pv[3] = (__bf16)a[3];
        pv[4] = (__bf16)bb[0]; pv[5] = (__bf16)bb[1];
        pv[6] = (__bf16)bb[2]; pv[7] = (__bf16)bb[3];
        pa[hh] = pv;
      }

      // PV: O[q][dd] += P * V ; vb shared across both halves
#pragma unroll
      for (int ntd = 0; ntd < 4; ++ntd) {
        const int cv = (((ks * 4 + quad) ^ f7)) * 8;   // V chunk ks*4+quad, swizzled
        bf16x8 vb = *(const bf16x8*)(sVc + (ntd * 16 + fr) * 64 + cv);
        o[0][ntd] = __builtin_amdgcn_mfma_f32_16x16x32_bf16(pa[0], vb, o[0][ntd], 0, 0, 0);
        o[1][ntd] = __builtin_amdgcn_mfma_f32_16x16x32_bf16(pa[1], vb, o[1][ntd], 0, 0, 0);
      }
    }

    if (kc < 15) __syncthreads();   // prefetch drained (vmcnt0) + all reads of cur done
  }

  // Denominator reduction via per-wave LDS scratch: lane(fr,quad) holds the
  // partial sum for q=fr over keys == quad*4+{0..3} (mod 16). Sum the 4 quads.
  red[wave][0][quad][fr] = l_run[0];
  red[wave][1][quad][fr] = l_run[1];
  __syncthreads();

#pragma unroll
  for (int hh = 0; hh < 2; ++hh) {
    float inv[4];
#pragma unroll
    for (int r = 0; r < 4; ++r) {
      const int ql = quad * 4 + r;   // q-within-16 of output row
      float d = red[wave][hh][0][ql] + red[wave][hh][1][ql] +
                red[wave][hh][2][ql] + red[wave][hh][3][ql];
      inv[r] = fast_rcp(d);
    }
#pragma unroll
    for (int ntd = 0; ntd < 4; ++ntd)
#pragma unroll
      for (int r = 0; r < 4; ++r) {
        const int row = q0 + hh * 64 + wave * 16 + quad * 4 + r;
        const int col = h * 64 + ntd * 16 + fr;
        Out[(size_t)(b * 2048 + row) * 1024 + col] = o[hh][ntd][r] * inv[r];
      }
  }
}

// ---------------- launch ----------------
extern "C" void kernel_launch(void* const* d_in, const int* in_sizes, int n_in,
                              void* d_out, int out_size, void* d_ws, size_t ws_size,
                              hipStream_t stream) {
  (void)in_sizes; (void)n_in; (void)out_size; (void)ws_size;
  const float* x   = (const float*)d_in[0];   // [4,2048,1024]
  const float* y   = (const float*)d_in[1];   // [4,1024,768]
  const int*   msk = (const int*)d_in[2];     // [4,2048]
  const float* Wq  = (const float*)d_in[3];   // [1024,1024]
  const float* Wkv = (const float*)d_in[4];   // [2048,768]
  float* out = (float*)d_out;                 // [4,2048,1024] f32

  char* ws = (char*)d_ws;
  const size_t MB = 1024 * 1024;
  u16* Xb   = (u16*)(ws + 0);        // 16 MB [8192][1024] mask-folded
  u16* Wqb  = (u16*)(ws + 16 * MB);  //  2 MB [1024][1024] * d^-0.5 * log2e
  u16* Yb   = (u16*)(ws + 18 * MB);  //  6 MB [4096][768]
  u16* Wkvb = (u16*)(ws + 24 * MB);  //  3 MB [2048][768]
  u16* Qb   = (u16*)(ws + 27 * MB);  // 16 MB [8192][1024]
  u16* KVb  = (u16*)(ws + 43 * MB);  // 16 MB [4096][2048] (only K half written/used)
  u16* Vtb  = (u16*)(ws + 59 * MB);  //  8 MB [4096][1024]  (high-water 67 MB)

  cvt_all<<<3456, 256, 0, stream>>>(x, Wq, y, Wkv, msk, Xb, Wqb, Yb, Wkvb);
  gemm_dual<<<1024, 256, 0, stream>>>(Xb, Wqb, Qb, Yb, Wkvb, KVb, Vtb);
  attn_kernel<<<1024, 256, 0, stream>>>(Qb, KVb, Vtb, out);
}